// Round 2
// baseline (1422.074 us; speedup 1.0000x reference)
//
#include <hip/hip_runtime.h>
#include <stdint.h>

// ---------- types / helpers ----------
using short8  = __attribute__((ext_vector_type(8))) short;
using float4v = __attribute__((ext_vector_type(4))) float;

__device__ __forceinline__ float b2f(unsigned short u) {
    union { unsigned int i; float f; } v; v.i = ((unsigned int)u) << 16; return v.f;
}
__device__ __forceinline__ unsigned short f2b(float f) {
    union { float f; unsigned int i; } v; v.f = f;
    unsigned int x = v.i;
    unsigned int r = (x + 0x7fffu + ((x >> 16) & 1u)) >> 16;   // RNE
    return (unsigned short)r;
}

__device__ __forceinline__ void gload_lds16(const void* g, void* l) {
    // async global->LDS, 16B/lane; LDS dest = wave-uniform base + lane*16
    __builtin_amdgcn_global_load_lds((const __attribute__((address_space(1))) void*)g,
                                     (__attribute__((address_space(3))) void*)l, 16, 0, 0);
}

// ---------- int degree counts (human keyed by src, bact keyed by dst) ----------
__global__ void count_deg(const int* __restrict__ src, const int* __restrict__ dst,
                          int* __restrict__ deg_h, int* __restrict__ deg_b, int E) {
    int e = blockIdx.x * blockDim.x + threadIdx.x;
    if (e < E) {
        atomicAdd(deg_h + src[e], 1);
        atomicAdd(deg_b + dst[e], 1);
    }
}

// ---------- 3-kernel exclusive scan over deg[N] -> row[N+1] ----------
__global__ void scan1(const int* __restrict__ deg, int* __restrict__ partial, int N) {
    int t = threadIdx.x;
    int base = blockIdx.x * 1024 + t * 4;
    int s = 0;
    #pragma unroll
    for (int i = 0; i < 4; ++i) { int idx = base + i; if (idx < N) s += deg[idx]; }
    #pragma unroll
    for (int off = 32; off; off >>= 1) s += __shfl_down(s, off);
    __shared__ int sm[4];
    if ((t & 63) == 0) sm[t >> 6] = s;
    __syncthreads();
    if (t == 0) partial[blockIdx.x] = sm[0] + sm[1] + sm[2] + sm[3];
}
__global__ void scan2(int* __restrict__ partial, int P) {
    if (blockIdx.x == 0 && threadIdx.x == 0) {
        int run = 0;
        for (int i = 0; i < P; ++i) { int v = partial[i]; partial[i] = run; run += v; }
    }
}
__global__ void scan3(const int* __restrict__ deg, const int* __restrict__ partial,
                      int* __restrict__ row, int N, int E) {
    int t = threadIdx.x;
    int lane = t & 63, wv = t >> 6;
    int base = blockIdx.x * 1024 + t * 4;
    int d[4]; int s = 0;
    #pragma unroll
    for (int i = 0; i < 4; ++i) { int idx = base + i; d[i] = (idx < N) ? deg[idx] : 0; s += d[i]; }
    int inc = s;
    #pragma unroll
    for (int off = 1; off < 64; off <<= 1) { int v = __shfl_up(inc, off); if (lane >= off) inc += v; }
    __shared__ int wsum[4];
    if (lane == 63) wsum[wv] = inc;
    __syncthreads();
    int woff = 0;
    for (int w = 0; w < wv; ++w) woff += wsum[w];
    int run = inc - s + woff + partial[blockIdx.x];
    #pragma unroll
    for (int i = 0; i < 4; ++i) { int idx = base + i; if (idx < N) row[idx] = run; run += d[i]; }
    if (blockIdx.x == 0 && t == 0) row[N] = E;
}

// ---------- bucket fill ----------
__global__ void fill_adj(const int* __restrict__ src, const int* __restrict__ dst,
                         int* __restrict__ cur_h, int* __restrict__ cur_b,
                         int* __restrict__ adj_h, int* __restrict__ adj_b, int E) {
    int e = blockIdx.x * blockDim.x + threadIdx.x;
    if (e < E) {
        int s = src[e], d = dst[e];
        adj_h[atomicAdd(cur_h + s, 1)] = d;
        adj_b[atomicAdd(cur_b + d, 1)] = s;
    }
}

// ---------- f32 -> bf16 elementwise convert ----------
__global__ void cvt_to_bf16(const float* __restrict__ in, unsigned short* __restrict__ out,
                            size_t n4) {
    size_t t = (size_t)blockIdx.x * blockDim.x + threadIdx.x;
    if (t >= n4) return;
    const float4 v = *(const float4*)(in + t * 4);
    ushort4 u;
    u.x = f2b(v.x); u.y = f2b(v.y); u.z = f2b(v.z); u.w = f2b(v.w);
    *(ushort4*)(out + t * 4) = u;
}

// ---------- CSR gather + mean + bf16 out ----------
// One wave per node; wave split into G row-groups of LPR lanes, 16B/lane.
// D=128: G=4 rows in flight per load instr; D=256: G=2.
template <int D>
__global__ __launch_bounds__(256)
void gather_mean(const unsigned short* __restrict__ x, const int* __restrict__ row,
                 const int* __restrict__ adj, unsigned short* __restrict__ out, int N) {
    constexpr int LPR = D / 8;        // lanes per row (8 bf16 = 16B each)
    constexpr int G   = 64 / LPR;     // rows processed in parallel
    int wid  = (blockIdx.x * blockDim.x + threadIdx.x) >> 6;
    int lane = threadIdx.x & 63;
    if (wid >= N) return;
    int beg = row[wid];
    int deg = row[wid + 1] - beg;

    const int g  = lane >> (LPR == 16 ? 4 : 5);   // group id
    const int gl = lane & (LPR - 1);              // lane within group

    float acc[8];
    #pragma unroll
    for (int p = 0; p < 8; ++p) acc[p] = 0.0f;

    for (int base = 0; base < deg; base += 64) {
        int nb_l = (base + lane < deg) ? adj[beg + base + lane] : 0;
        int m = deg - base; if (m > 64) m = 64;
        for (int j = 0; j < m; j += G) {
            int idx = j + g;                       // this group's neighbor slot
            int nb = __shfl(nb_l, idx);            // idx < 64 always (j mult of G)
            if (idx < m) {
                const short8 v = *(const short8*)(x + (size_t)nb * D + gl * 8);
                #pragma unroll
                for (int p = 0; p < 8; ++p) acc[p] += b2f((unsigned short)v[p]);
            }
        }
    }
    // cross-group reduction: combine lanes {l, l^LPR, ...}
    #pragma unroll
    for (int off = LPR; off < 64; off <<= 1) {
        #pragma unroll
        for (int p = 0; p < 8; ++p) acc[p] += __shfl_xor(acc[p], off);
    }
    float inv = 1.0f / (float)((deg > 0) ? deg : 1);
    if (lane < LPR) {
        unsigned short* op = out + (size_t)wid * D + lane * 8;
        short8 u;
        #pragma unroll
        for (int p = 0; p < 8; ++p) u[p] = (short)f2b(acc[p] * inv);
        *(short8*)op = u;
    }
}

// ---------- weight transpose + convert: W f32 [K][256] -> Wt bf16 [256][K] ----------
__global__ void transpose_w(const float* __restrict__ W,
                            unsigned short* __restrict__ Wt, int K) {
    int k = blockIdx.x;        // [0,K)
    int c = threadIdx.x;       // [0,256)
    Wt[(size_t)c * K + k] = f2b(W[(size_t)k * 256 + c]);
}

// ---------- fused GEMM: res = relu(A0@B0^T + A1@B1^T + bias) ----------
template <bool F32OUT>
__global__ __launch_bounds__(256, 3)
void gemm_fused(const unsigned short* __restrict__ A0, const unsigned short* __restrict__ A1,
                const unsigned short* __restrict__ B0, const unsigned short* __restrict__ B1,
                const float* __restrict__ bias,
                float* __restrict__ outf, unsigned short* __restrict__ outb,
                int M, int K) {
    __shared__ unsigned short As[64 * 64];    // 8 KB
    __shared__ unsigned short Bs[256 * 64];   // 32 KB
    const int tid  = threadIdx.x;
    const int wave = tid >> 6, lane = tid & 63;
    const int wn   = wave;
    const int row0 = blockIdx.x * 64;

    float4v acc[4][4];
    #pragma unroll
    for (int i = 0; i < 4; ++i)
        #pragma unroll
        for (int j = 0; j < 4; ++j) acc[i][j] = (float4v){0.f, 0.f, 0.f, 0.f};

    const int r  = lane >> 3;
    const int cg = lane & 7;
    const int kchunks = K >> 6;
    const int nchunks = kchunks * 2;

    for (int c = 0; c < nchunks; ++c) {
        const unsigned short* Aseg = (c < kchunks) ? A0 : A1;
        const unsigned short* Bseg = (c < kchunks) ? B0 : B1;
        const int k0 = ((c < kchunks) ? c : c - kchunks) << 6;

        if (c) __syncthreads();
        {   // stage A: 64 rows; 16 rows per wave
            int rr = wave * 16;
            const unsigned short* gp = Aseg + (size_t)(row0 + rr + r) * K + k0 + cg * 8;
            unsigned short* lp = As + rr * 64;
            if (row0 + rr + r < M)     gload_lds16(gp, lp);
            if (row0 + rr + 8 + r < M) gload_lds16(gp + 8 * (size_t)K, lp + 8 * 64);
        }
        {   // stage B: 256 rows; 64 rows per wave
            int rr = wave * 64;
            const unsigned short* gp = Bseg + (size_t)(rr + r) * K + k0 + cg * 8;
            unsigned short* lp = Bs + rr * 64;
            #pragma unroll
            for (int i = 0; i < 8; ++i)
                gload_lds16(gp + (size_t)(i * 8) * K, lp + i * 8 * 64);
        }
        __syncthreads();

        const int q8 = (lane >> 4) * 8;
        const int l15 = lane & 15;
        #pragma unroll
        for (int kk = 0; kk <= 32; kk += 32) {
            short8 af[4], bf[4];
            #pragma unroll
            for (int f = 0; f < 4; ++f)
                af[f] = *(const short8*)(As + (f * 16 + l15) * 64 + kk + q8);
            #pragma unroll
            for (int f = 0; f < 4; ++f)
                bf[f] = *(const short8*)(Bs + (wn * 64 + f * 16 + l15) * 64 + kk + q8);
            #pragma unroll
            for (int fm = 0; fm < 4; ++fm)
                #pragma unroll
                for (int fn = 0; fn < 4; ++fn)
                    acc[fm][fn] = __builtin_amdgcn_mfma_f32_16x16x32_bf16(
                        af[fm], bf[fn], acc[fm][fn], 0, 0, 0);
        }
    }

    // epilogue: C/D layout col=lane&15, row=(lane>>4)*4+reg  [verified m89/m91]
    const int l15 = lane & 15;
    const int rq  = (lane >> 4) * 4;
    #pragma unroll
    for (int fn = 0; fn < 4; ++fn) {
        int col = wn * 64 + fn * 16 + l15;
        float bv = bias[col];
        #pragma unroll
        for (int fm = 0; fm < 4; ++fm) {
            #pragma unroll
            for (int rg = 0; rg < 4; ++rg) {
                int row = row0 + fm * 16 + rq + rg;
                if (row < M) {
                    float v = fmaxf(acc[fm][fn][rg] + bv, 0.0f);
                    if (F32OUT) outf[(size_t)row * 256 + col] = v;
                    else        outb[(size_t)row * 256 + col] = f2b(v);
                }
            }
        }
    }
}

// ---------- launcher ----------
extern "C" void kernel_launch(void* const* d_in, const int* in_sizes, int n_in,
                              void* d_out, int out_size, void* d_ws, size_t ws_size,
                              hipStream_t stream) {
    const int DIN = 128, H = 256;
    const int N = in_sizes[0] / DIN;
    const int E = in_sizes[2] / 2;

    const float* xh = (const float*)d_in[0];
    const float* xb = (const float*)d_in[1];
    const int* ei  = (const int*)d_in[2];
    const int* src = ei;
    const int* dst = ei + E;
    const float* h1Wl = (const float*)d_in[3];
    const float* h1Wr = (const float*)d_in[4];
    const float* h1b  = (const float*)d_in[5];
    const float* h2Wl = (const float*)d_in[6];
    const float* h2Wr = (const float*)d_in[7];
    const float* h2b  = (const float*)d_in[8];
    const float* b1Wl = (const float*)d_in[9];
    const float* b1Wr = (const float*)d_in[10];
    const float* b1b  = (const float*)d_in[11];
    const float* b2Wl = (const float*)d_in[12];
    const float* b2Wr = (const float*)d_in[13];
    const float* b2b  = (const float*)d_in[14];

    float* outH = (float*)d_out;
    float* outB = outH + (size_t)N * H;

    // ---- ws layout ----
    int* deg_h = (int*)d_ws;
    int* deg_b = deg_h + N;
    int* row_h = deg_b + N;
    int* row_b = row_h + (N + 1);
    int* cur_h = row_b + (N + 1);
    int* cur_b = cur_h + N;
    int* partial = cur_b + N;          // up to 256 chunk sums
    int* adj_h = partial + 256;
    int* adj_b = adj_h + E;
    // round bf16 region up to 64B so all 16B vector accesses are naturally aligned
    uintptr_t up = (uintptr_t)(adj_b + E);
    up = (up + 63) & ~(uintptr_t)63;
    unsigned short* wtp = (unsigned short*)up;
    unsigned short* t_h1l = wtp; wtp += DIN * H;
    unsigned short* t_h1r = wtp; wtp += DIN * H;
    unsigned short* t_h2l = wtp; wtp += H * H;
    unsigned short* t_h2r = wtp; wtp += H * H;
    unsigned short* t_b1l = wtp; wtp += DIN * H;
    unsigned short* t_b1r = wtp; wtp += DIN * H;
    unsigned short* t_b2l = wtp; wtp += H * H;
    unsigned short* t_b2r = wtp; wtp += H * H;
    unsigned short* xbf   = wtp;
    unsigned short* aggbf = xbf + (size_t)N * DIN;
    unsigned short* hbf   = aggbf + (size_t)N * H;

    const int BLK = 256;
    dim3 blk(BLK);
    const int P = (N + 1023) / 1024;   // scan chunks

    // ---- build CSRs ----
    hipMemsetAsync(deg_h, 0, (size_t)2 * N * sizeof(int), stream);
    count_deg<<<dim3((E + BLK - 1) / BLK), blk, 0, stream>>>(src, dst, deg_h, deg_b, E);

    scan1<<<dim3(P), blk, 0, stream>>>(deg_h, partial, N);
    scan2<<<dim3(1), blk, 0, stream>>>(partial, P);
    scan3<<<dim3(P), blk, 0, stream>>>(deg_h, partial, row_h, N, E);
    scan1<<<dim3(P), blk, 0, stream>>>(deg_b, partial, N);
    scan2<<<dim3(1), blk, 0, stream>>>(partial, P);
    scan3<<<dim3(P), blk, 0, stream>>>(deg_b, partial, row_b, N, E);

    hipMemcpyAsync(cur_h, row_h, (size_t)N * sizeof(int), hipMemcpyDeviceToDevice, stream);
    hipMemcpyAsync(cur_b, row_b, (size_t)N * sizeof(int), hipMemcpyDeviceToDevice, stream);
    fill_adj<<<dim3((E + BLK - 1) / BLK), blk, 0, stream>>>(src, dst, cur_h, cur_b,
                                                            adj_h, adj_b, E);

    // ---- weight transposes ----
    transpose_w<<<dim3(DIN), blk, 0, stream>>>(h1Wl, t_h1l, DIN);
    transpose_w<<<dim3(DIN), blk, 0, stream>>>(h1Wr, t_h1r, DIN);
    transpose_w<<<dim3(H),   blk, 0, stream>>>(h2Wl, t_h2l, H);
    transpose_w<<<dim3(H),   blk, 0, stream>>>(h2Wr, t_h2r, H);
    transpose_w<<<dim3(DIN), blk, 0, stream>>>(b1Wl, t_b1l, DIN);
    transpose_w<<<dim3(DIN), blk, 0, stream>>>(b1Wr, t_b1r, DIN);
    transpose_w<<<dim3(H),   blk, 0, stream>>>(b2Wl, t_b2l, H);
    transpose_w<<<dim3(H),   blk, 0, stream>>>(b2Wr, t_b2r, H);

    dim3 nggrid((N + 3) / 4);                      // gather: wave per node, 4 waves/block
    dim3 ggrid((N + 63) / 64);                     // GEMM: 64 rows per block
    int ncvt = ((size_t)N * DIN / 4 + BLK - 1) / BLK;

    // ---- human branch ----
    cvt_to_bf16<<<dim3(ncvt), blk, 0, stream>>>(xh, xbf, (size_t)N * DIN / 4);
    gather_mean<128><<<nggrid, blk, 0, stream>>>(xbf, row_h, adj_h, aggbf, N);
    gemm_fused<false><<<ggrid, blk, 0, stream>>>(aggbf, xbf, t_h1l, t_h1r, h1b,
                                                 nullptr, hbf, N, DIN);
    gather_mean<256><<<nggrid, blk, 0, stream>>>(hbf, row_h, adj_h, aggbf, N);
    gemm_fused<true><<<ggrid, blk, 0, stream>>>(aggbf, hbf, t_h2l, t_h2r, h2b,
                                                outH, nullptr, N, H);

    // ---- bacterial branch ----
    cvt_to_bf16<<<dim3(ncvt), blk, 0, stream>>>(xb, xbf, (size_t)N * DIN / 4);
    gather_mean<128><<<nggrid, blk, 0, stream>>>(xbf, row_b, adj_b, aggbf, N);
    gemm_fused<false><<<ggrid, blk, 0, stream>>>(aggbf, xbf, t_b1l, t_b1r, b1b,
                                                 nullptr, hbf, N, DIN);
    gather_mean<256><<<nggrid, blk, 0, stream>>>(hbf, row_b, adj_b, aggbf, N);
    gemm_fused<true><<<ggrid, blk, 0, stream>>>(aggbf, hbf, t_b2l, t_b2r, b2b,
                                                outB, nullptr, N, H);
}

// Round 3
// 1287.697 us; speedup vs baseline: 1.1044x; 1.1044x over previous
//
#include <hip/hip_runtime.h>
#include <stdint.h>

// ---------- types / helpers ----------
using short8  = __attribute__((ext_vector_type(8))) short;
using float4v = __attribute__((ext_vector_type(4))) float;

__device__ __forceinline__ float b2f(unsigned short u) {
    union { unsigned int i; float f; } v; v.i = ((unsigned int)u) << 16; return v.f;
}
__device__ __forceinline__ unsigned short f2b(float f) {
    union { float f; unsigned int i; } v; v.f = f;
    unsigned int x = v.i;
    unsigned int r = (x + 0x7fffu + ((x >> 16) & 1u)) >> 16;   // RNE
    return (unsigned short)r;
}

__device__ __forceinline__ void gload_lds16(const void* g, void* l) {
    // async global->LDS, 16B/lane; LDS dest = wave-uniform base + lane*16
    __builtin_amdgcn_global_load_lds((const __attribute__((address_space(1))) void*)g,
                                     (__attribute__((address_space(3))) void*)l, 16, 0, 0);
}

// ---------- int degree counts (human keyed by src, bact keyed by dst) ----------
__global__ void count_deg(const int* __restrict__ src, const int* __restrict__ dst,
                          int* __restrict__ deg_h, int* __restrict__ deg_b, int E) {
    int e = blockIdx.x * blockDim.x + threadIdx.x;
    if (e < E) {
        atomicAdd(deg_h + src[e], 1);
        atomicAdd(deg_b + dst[e], 1);
    }
}

// ---------- 3-kernel exclusive scan over deg[N] -> row[N+1] ----------
__global__ void scan1(const int* __restrict__ deg, int* __restrict__ partial, int N) {
    int t = threadIdx.x;
    int base = blockIdx.x * 1024 + t * 4;
    int s = 0;
    #pragma unroll
    for (int i = 0; i < 4; ++i) { int idx = base + i; if (idx < N) s += deg[idx]; }
    #pragma unroll
    for (int off = 32; off; off >>= 1) s += __shfl_down(s, off);
    __shared__ int sm[4];
    if ((t & 63) == 0) sm[t >> 6] = s;
    __syncthreads();
    if (t == 0) partial[blockIdx.x] = sm[0] + sm[1] + sm[2] + sm[3];
}
__global__ void scan2(int* __restrict__ partial, int P) {
    if (blockIdx.x == 0 && threadIdx.x == 0) {
        int run = 0;
        for (int i = 0; i < P; ++i) { int v = partial[i]; partial[i] = run; run += v; }
    }
}
__global__ void scan3(const int* __restrict__ deg, const int* __restrict__ partial,
                      int* __restrict__ row, int N, int E) {
    int t = threadIdx.x;
    int lane = t & 63, wv = t >> 6;
    int base = blockIdx.x * 1024 + t * 4;
    int d[4]; int s = 0;
    #pragma unroll
    for (int i = 0; i < 4; ++i) { int idx = base + i; d[i] = (idx < N) ? deg[idx] : 0; s += d[i]; }
    int inc = s;
    #pragma unroll
    for (int off = 1; off < 64; off <<= 1) { int v = __shfl_up(inc, off); if (lane >= off) inc += v; }
    __shared__ int wsum[4];
    if (lane == 63) wsum[wv] = inc;
    __syncthreads();
    int woff = 0;
    for (int w = 0; w < wv; ++w) woff += wsum[w];
    int run = inc - s + woff + partial[blockIdx.x];
    #pragma unroll
    for (int i = 0; i < 4; ++i) { int idx = base + i; if (idx < N) row[idx] = run; run += d[i]; }
    if (blockIdx.x == 0 && t == 0) row[N] = E;
}

// ---------- XCD-ranged bucket fill ----------
// Node space split into 8 ranges. Block r = blockIdx.x&7 commits only keys in
// range r; under round-robin dispatch consecutive r land on distinct XCDs, so
// each XCD's write region (~E/8*4B = 800KB) stays L2-resident and each node's
// 64B bucket collects all its stores before one writeback. Correct under ANY
// block->XCD mapping (mapping only affects locality). Edge list re-read 8x
// (sequential, cheap) vs 16x cut in HBM write-allocate traffic.
__global__ __launch_bounds__(256)
void fill_adj_ranged(const int* __restrict__ src, const int* __restrict__ dst,
                     int* __restrict__ cur_h, int* __restrict__ cur_b,
                     int* __restrict__ adj_h, int* __restrict__ adj_b,
                     int E, int N, int nch) {
    const int NR = 8;
    int r     = blockIdx.x & (NR - 1);
    int chunk = blockIdx.x >> 3;
    int rng = (N + NR - 1) / NR;
    int lo = r * rng;
    int hi = lo + rng; if (hi > N) hi = N;
    int per = (E + nch - 1) / nch;
    int e0 = chunk * per;
    int e1 = e0 + per; if (e1 > E) e1 = E;
    for (int e = e0 + (int)threadIdx.x; e < e1; e += 256) {
        int s = src[e], d = dst[e];
        if (s >= lo && s < hi) adj_h[atomicAdd(cur_h + s, 1)] = d;
        if (d >= lo && d < hi) adj_b[atomicAdd(cur_b + d, 1)] = s;
    }
}

// ---------- f32 -> bf16 elementwise convert ----------
__global__ void cvt_to_bf16(const float* __restrict__ in, unsigned short* __restrict__ out,
                            size_t n4) {
    size_t t = (size_t)blockIdx.x * blockDim.x + threadIdx.x;
    if (t >= n4) return;
    const float4 v = *(const float4*)(in + t * 4);
    ushort4 u;
    u.x = f2b(v.x); u.y = f2b(v.y); u.z = f2b(v.z); u.w = f2b(v.w);
    *(ushort4*)(out + t * 4) = u;
}

// ---------- CSR gather + mean + bf16 out ----------
// One wave per node; wave split into G row-groups of LPR lanes, 16B/lane.
// Main loop pipelined UNR=16/G deep: 16 neighbor rows in flight per wave
// before the first waitcnt (loads batched via independent temporaries).
template <int D>
__global__ __launch_bounds__(256)
void gather_mean(const unsigned short* __restrict__ x, const int* __restrict__ row,
                 const int* __restrict__ adj, unsigned short* __restrict__ out, int N) {
    constexpr int LPR = D / 8;        // lanes per row (8 bf16 = 16B each)
    constexpr int G   = 64 / LPR;     // rows processed in parallel per instr
    constexpr int UNR = 16 / G;       // pipeline depth (rows in flight = 16)
    int wid  = (blockIdx.x * blockDim.x + threadIdx.x) >> 6;
    int lane = threadIdx.x & 63;
    if (wid >= N) return;
    int beg = row[wid];
    int deg = row[wid + 1] - beg;

    const int g  = lane >> (LPR == 16 ? 4 : 5);   // group id
    const int gl = lane & (LPR - 1);              // lane within group

    float acc[8];
    #pragma unroll
    for (int p = 0; p < 8; ++p) acc[p] = 0.0f;

    for (int base = 0; base < deg; base += 64) {
        int nb_l = (base + lane < deg) ? adj[beg + base + lane] : 0;
        int m = deg - base; if (m > 64) m = 64;
        int j = 0;
        // pipelined main loop: issue UNR loads, then accumulate
        for (; j + UNR * G <= m; j += UNR * G) {
            int nn[UNR];
            #pragma unroll
            for (int u = 0; u < UNR; ++u) nn[u] = __shfl(nb_l, j + u * G + g);
            short8 vv[UNR];
            #pragma unroll
            for (int u = 0; u < UNR; ++u)
                vv[u] = *(const short8*)(x + (size_t)nn[u] * D + gl * 8);
            #pragma unroll
            for (int u = 0; u < UNR; ++u)
                #pragma unroll
                for (int p = 0; p < 8; ++p) acc[p] += b2f((unsigned short)vv[u][p]);
        }
        // tail
        for (; j < m; j += G) {
            int idx = j + g;
            int nb = __shfl(nb_l, idx);
            if (idx < m) {
                const short8 v = *(const short8*)(x + (size_t)nb * D + gl * 8);
                #pragma unroll
                for (int p = 0; p < 8; ++p) acc[p] += b2f((unsigned short)v[p]);
            }
        }
    }
    // cross-group reduction: combine lanes {l, l^LPR, ...}
    #pragma unroll
    for (int off = LPR; off < 64; off <<= 1) {
        #pragma unroll
        for (int p = 0; p < 8; ++p) acc[p] += __shfl_xor(acc[p], off);
    }
    float inv = 1.0f / (float)((deg > 0) ? deg : 1);
    if (lane < LPR) {
        unsigned short* op = out + (size_t)wid * D + lane * 8;
        short8 u;
        #pragma unroll
        for (int p = 0; p < 8; ++p) u[p] = (short)f2b(acc[p] * inv);
        *(short8*)op = u;
    }
}

// ---------- weight transpose + convert: W f32 [K][256] -> Wt bf16 [256][K] ----------
__global__ void transpose_w(const float* __restrict__ W,
                            unsigned short* __restrict__ Wt, int K) {
    int k = blockIdx.x;        // [0,K)
    int c = threadIdx.x;       // [0,256)
    Wt[(size_t)c * K + k] = f2b(W[(size_t)k * 256 + c]);
}

// ---------- fused GEMM: res = relu(A0@B0^T + A1@B1^T + bias) ----------
template <bool F32OUT>
__global__ __launch_bounds__(256, 3)
void gemm_fused(const unsigned short* __restrict__ A0, const unsigned short* __restrict__ A1,
                const unsigned short* __restrict__ B0, const unsigned short* __restrict__ B1,
                const float* __restrict__ bias,
                float* __restrict__ outf, unsigned short* __restrict__ outb,
                int M, int K) {
    __shared__ unsigned short As[64 * 64];    // 8 KB
    __shared__ unsigned short Bs[256 * 64];   // 32 KB
    const int tid  = threadIdx.x;
    const int wave = tid >> 6, lane = tid & 63;
    const int wn   = wave;
    const int row0 = blockIdx.x * 64;

    float4v acc[4][4];
    #pragma unroll
    for (int i = 0; i < 4; ++i)
        #pragma unroll
        for (int j = 0; j < 4; ++j) acc[i][j] = (float4v){0.f, 0.f, 0.f, 0.f};

    const int r  = lane >> 3;
    const int cg = lane & 7;
    const int kchunks = K >> 6;
    const int nchunks = kchunks * 2;

    for (int c = 0; c < nchunks; ++c) {
        const unsigned short* Aseg = (c < kchunks) ? A0 : A1;
        const unsigned short* Bseg = (c < kchunks) ? B0 : B1;
        const int k0 = ((c < kchunks) ? c : c - kchunks) << 6;

        if (c) __syncthreads();
        {   // stage A: 64 rows; 16 rows per wave
            int rr = wave * 16;
            const unsigned short* gp = Aseg + (size_t)(row0 + rr + r) * K + k0 + cg * 8;
            unsigned short* lp = As + rr * 64;
            if (row0 + rr + r < M)     gload_lds16(gp, lp);
            if (row0 + rr + 8 + r < M) gload_lds16(gp + 8 * (size_t)K, lp + 8 * 64);
        }
        {   // stage B: 256 rows; 64 rows per wave
            int rr = wave * 64;
            const unsigned short* gp = Bseg + (size_t)(rr + r) * K + k0 + cg * 8;
            unsigned short* lp = Bs + rr * 64;
            #pragma unroll
            for (int i = 0; i < 8; ++i)
                gload_lds16(gp + (size_t)(i * 8) * K, lp + i * 8 * 64);
        }
        __syncthreads();

        const int q8 = (lane >> 4) * 8;
        const int l15 = lane & 15;
        #pragma unroll
        for (int kk = 0; kk <= 32; kk += 32) {
            short8 af[4], bf[4];
            #pragma unroll
            for (int f = 0; f < 4; ++f)
                af[f] = *(const short8*)(As + (f * 16 + l15) * 64 + kk + q8);
            #pragma unroll
            for (int f = 0; f < 4; ++f)
                bf[f] = *(const short8*)(Bs + (wn * 64 + f * 16 + l15) * 64 + kk + q8);
            #pragma unroll
            for (int fm = 0; fm < 4; ++fm)
                #pragma unroll
                for (int fn = 0; fn < 4; ++fn)
                    acc[fm][fn] = __builtin_amdgcn_mfma_f32_16x16x32_bf16(
                        af[fm], bf[fn], acc[fm][fn], 0, 0, 0);
        }
    }

    // epilogue: C/D layout col=lane&15, row=(lane>>4)*4+reg  [verified m89/m91]
    const int l15 = lane & 15;
    const int rq  = (lane >> 4) * 4;
    #pragma unroll
    for (int fn = 0; fn < 4; ++fn) {
        int col = wn * 64 + fn * 16 + l15;
        float bv = bias[col];
        #pragma unroll
        for (int fm = 0; fm < 4; ++fm) {
            #pragma unroll
            for (int rg = 0; rg < 4; ++rg) {
                int row = row0 + fm * 16 + rq + rg;
                if (row < M) {
                    float v = fmaxf(acc[fm][fn][rg] + bv, 0.0f);
                    if (F32OUT) outf[(size_t)row * 256 + col] = v;
                    else        outb[(size_t)row * 256 + col] = f2b(v);
                }
            }
        }
    }
}

// ---------- launcher ----------
extern "C" void kernel_launch(void* const* d_in, const int* in_sizes, int n_in,
                              void* d_out, int out_size, void* d_ws, size_t ws_size,
                              hipStream_t stream) {
    const int DIN = 128, H = 256;
    const int N = in_sizes[0] / DIN;
    const int E = in_sizes[2] / 2;

    const float* xh = (const float*)d_in[0];
    const float* xb = (const float*)d_in[1];
    const int* ei  = (const int*)d_in[2];
    const int* src = ei;
    const int* dst = ei + E;
    const float* h1Wl = (const float*)d_in[3];
    const float* h1Wr = (const float*)d_in[4];
    const float* h1b  = (const float*)d_in[5];
    const float* h2Wl = (const float*)d_in[6];
    const float* h2Wr = (const float*)d_in[7];
    const float* h2b  = (const float*)d_in[8];
    const float* b1Wl = (const float*)d_in[9];
    const float* b1Wr = (const float*)d_in[10];
    const float* b1b  = (const float*)d_in[11];
    const float* b2Wl = (const float*)d_in[12];
    const float* b2Wr = (const float*)d_in[13];
    const float* b2b  = (const float*)d_in[14];

    float* outH = (float*)d_out;
    float* outB = outH + (size_t)N * H;

    // ---- ws layout ----
    int* deg_h = (int*)d_ws;
    int* deg_b = deg_h + N;
    int* row_h = deg_b + N;
    int* row_b = row_h + (N + 1);
    int* cur_h = row_b + (N + 1);
    int* cur_b = cur_h + N;
    int* partial = cur_b + N;          // up to 256 chunk sums
    int* adj_h = partial + 256;
    int* adj_b = adj_h + E;
    // round bf16 region up to 64B so all 16B vector accesses are naturally aligned
    uintptr_t up = (uintptr_t)(adj_b + E);
    up = (up + 63) & ~(uintptr_t)63;
    unsigned short* wtp = (unsigned short*)up;
    unsigned short* t_h1l = wtp; wtp += DIN * H;
    unsigned short* t_h1r = wtp; wtp += DIN * H;
    unsigned short* t_h2l = wtp; wtp += H * H;
    unsigned short* t_h2r = wtp; wtp += H * H;
    unsigned short* t_b1l = wtp; wtp += DIN * H;
    unsigned short* t_b1r = wtp; wtp += DIN * H;
    unsigned short* t_b2l = wtp; wtp += H * H;
    unsigned short* t_b2r = wtp; wtp += H * H;
    unsigned short* xbf   = wtp;
    unsigned short* aggbf = xbf + (size_t)N * DIN;
    unsigned short* hbf   = aggbf + (size_t)N * H;

    const int BLK = 256;
    dim3 blk(BLK);
    const int P = (N + 1023) / 1024;   // scan chunks

    // ---- build CSRs ----
    hipMemsetAsync(deg_h, 0, (size_t)2 * N * sizeof(int), stream);
    count_deg<<<dim3((E + BLK - 1) / BLK), blk, 0, stream>>>(src, dst, deg_h, deg_b, E);

    scan1<<<dim3(P), blk, 0, stream>>>(deg_h, partial, N);
    scan2<<<dim3(1), blk, 0, stream>>>(partial, P);
    scan3<<<dim3(P), blk, 0, stream>>>(deg_h, partial, row_h, N, E);
    scan1<<<dim3(P), blk, 0, stream>>>(deg_b, partial, N);
    scan2<<<dim3(1), blk, 0, stream>>>(partial, P);
    scan3<<<dim3(P), blk, 0, stream>>>(deg_b, partial, row_b, N, E);

    hipMemcpyAsync(cur_h, row_h, (size_t)N * sizeof(int), hipMemcpyDeviceToDevice, stream);
    hipMemcpyAsync(cur_b, row_b, (size_t)N * sizeof(int), hipMemcpyDeviceToDevice, stream);
    {   // ranged fill: 256 edge-chunks x 8 node-ranges = 2048 blocks
        const int NCH = 256;
        fill_adj_ranged<<<dim3(NCH * 8), blk, 0, stream>>>(src, dst, cur_h, cur_b,
                                                           adj_h, adj_b, E, N, NCH);
    }

    // ---- weight transposes ----
    transpose_w<<<dim3(DIN), blk, 0, stream>>>(h1Wl, t_h1l, DIN);
    transpose_w<<<dim3(DIN), blk, 0, stream>>>(h1Wr, t_h1r, DIN);
    transpose_w<<<dim3(H),   blk, 0, stream>>>(h2Wl, t_h2l, H);
    transpose_w<<<dim3(H),   blk, 0, stream>>>(h2Wr, t_h2r, H);
    transpose_w<<<dim3(DIN), blk, 0, stream>>>(b1Wl, t_b1l, DIN);
    transpose_w<<<dim3(DIN), blk, 0, stream>>>(b1Wr, t_b1r, DIN);
    transpose_w<<<dim3(H),   blk, 0, stream>>>(b2Wl, t_b2l, H);
    transpose_w<<<dim3(H),   blk, 0, stream>>>(b2Wr, t_b2r, H);

    dim3 nggrid((N + 3) / 4);                      // gather: wave per node, 4 waves/block
    dim3 ggrid((N + 63) / 64);                     // GEMM: 64 rows per block
    int ncvt = ((size_t)N * DIN / 4 + BLK - 1) / BLK;

    // ---- human branch ----
    cvt_to_bf16<<<dim3(ncvt), blk, 0, stream>>>(xh, xbf, (size_t)N * DIN / 4);
    gather_mean<128><<<nggrid, blk, 0, stream>>>(xbf, row_h, adj_h, aggbf, N);
    gemm_fused<false><<<ggrid, blk, 0, stream>>>(aggbf, xbf, t_h1l, t_h1r, h1b,
                                                 nullptr, hbf, N, DIN);
    gather_mean<256><<<nggrid, blk, 0, stream>>>(hbf, row_h, adj_h, aggbf, N);
    gemm_fused<true><<<ggrid, blk, 0, stream>>>(aggbf, hbf, t_h2l, t_h2r, h2b,
                                                outH, nullptr, N, H);

    // ---- bacterial branch ----
    cvt_to_bf16<<<dim3(ncvt), blk, 0, stream>>>(xb, xbf, (size_t)N * DIN / 4);
    gather_mean<128><<<nggrid, blk, 0, stream>>>(xbf, row_b, adj_b, aggbf, N);
    gemm_fused<false><<<ggrid, blk, 0, stream>>>(aggbf, xbf, t_b1l, t_b1r, b1b,
                                                 nullptr, hbf, N, DIN);
    gather_mean<256><<<nggrid, blk, 0, stream>>>(hbf, row_b, adj_b, aggbf, N);
    gemm_fused<true><<<ggrid, blk, 0, stream>>>(aggbf, hbf, t_b2l, t_b2r, b2b,
                                                outB, nullptr, N, H);
}

// Round 4
// 1285.154 us; speedup vs baseline: 1.1065x; 1.0020x over previous
//
#include <hip/hip_runtime.h>
#include <stdint.h>

// ---------- types / helpers ----------
using short8  = __attribute__((ext_vector_type(8))) short;
using float4v = __attribute__((ext_vector_type(4))) float;

__device__ __forceinline__ float b2f(unsigned short u) {
    union { unsigned int i; float f; } v; v.i = ((unsigned int)u) << 16; return v.f;
}
__device__ __forceinline__ unsigned short f2b(float f) {
    union { float f; unsigned int i; } v; v.f = f;
    unsigned int x = v.i;
    unsigned int r = (x + 0x7fffu + ((x >> 16) & 1u)) >> 16;   // RNE
    return (unsigned short)r;
}

__device__ __forceinline__ void gload_lds16(const void* g, void* l) {
    // async global->LDS, 16B/lane; LDS dest = wave-uniform base + lane*16
    __builtin_amdgcn_global_load_lds((const __attribute__((address_space(1))) void*)g,
                                     (__attribute__((address_space(3))) void*)l, 16, 0, 0);
}

// ---------- int degree counts (human keyed by src, bact keyed by dst) ----------
// nt loads: edge stream must not evict the deg arrays from L2.
__global__ void count_deg(const int* __restrict__ src, const int* __restrict__ dst,
                          int* __restrict__ deg_h, int* __restrict__ deg_b, int E) {
    int e = blockIdx.x * blockDim.x + threadIdx.x;
    if (e < E) {
        int s = __builtin_nontemporal_load(src + e);
        int d = __builtin_nontemporal_load(dst + e);
        atomicAdd(deg_h + s, 1);
        atomicAdd(deg_b + d, 1);
    }
}

// ---------- 3-kernel exclusive scan over deg[N] -> row[N+1] ----------
__global__ void scan1(const int* __restrict__ deg, int* __restrict__ partial, int N) {
    int t = threadIdx.x;
    int base = blockIdx.x * 1024 + t * 4;
    int s = 0;
    #pragma unroll
    for (int i = 0; i < 4; ++i) { int idx = base + i; if (idx < N) s += deg[idx]; }
    #pragma unroll
    for (int off = 32; off; off >>= 1) s += __shfl_down(s, off);
    __shared__ int sm[4];
    if ((t & 63) == 0) sm[t >> 6] = s;
    __syncthreads();
    if (t == 0) partial[blockIdx.x] = sm[0] + sm[1] + sm[2] + sm[3];
}
__global__ void scan2(int* __restrict__ partial, int P) {
    if (blockIdx.x == 0 && threadIdx.x == 0) {
        int run = 0;
        for (int i = 0; i < P; ++i) { int v = partial[i]; partial[i] = run; run += v; }
    }
}
__global__ void scan3(const int* __restrict__ deg, const int* __restrict__ partial,
                      int* __restrict__ row, int N, int E) {
    int t = threadIdx.x;
    int lane = t & 63, wv = t >> 6;
    int base = blockIdx.x * 1024 + t * 4;
    int d[4]; int s = 0;
    #pragma unroll
    for (int i = 0; i < 4; ++i) { int idx = base + i; d[i] = (idx < N) ? deg[idx] : 0; s += d[i]; }
    int inc = s;
    #pragma unroll
    for (int off = 1; off < 64; off <<= 1) { int v = __shfl_up(inc, off); if (lane >= off) inc += v; }
    __shared__ int wsum[4];
    if (lane == 63) wsum[wv] = inc;
    __syncthreads();
    int woff = 0;
    for (int w = 0; w < wv; ++w) woff += wsum[w];
    int run = inc - s + woff + partial[blockIdx.x];
    #pragma unroll
    for (int i = 0; i < 4; ++i) { int idx = base + i; if (idx < N) row[idx] = run; run += d[i]; }
    if (blockIdx.x == 0 && t == 0) row[N] = E;
}

// ---------- XCD-ranged bucket fill ----------
// Node space split into 8 ranges; block r = blockIdx.x&7 commits only keys in
// range r (round-robin -> XCD r, locality heuristic only; correct under any
// mapping). nt loads on the edge stream keep the range's adj slice (1.6MB) +
// cur slice (0.8MB) L2-resident so each node's 64B bucket collects all ~16
// stores before one writeback.
__global__ __launch_bounds__(256)
void fill_adj_ranged(const int* __restrict__ src, const int* __restrict__ dst,
                     int* __restrict__ cur_h, int* __restrict__ cur_b,
                     int* __restrict__ adj_h, int* __restrict__ adj_b,
                     int E, int N, int nch) {
    const int NR = 8;
    int r     = blockIdx.x & (NR - 1);
    int chunk = blockIdx.x >> 3;
    int rng = (N + NR - 1) / NR;
    int lo = r * rng;
    int hi = lo + rng; if (hi > N) hi = N;
    int per = (E + nch - 1) / nch;
    int e0 = chunk * per;
    int e1 = e0 + per; if (e1 > E) e1 = E;
    for (int e = e0 + (int)threadIdx.x; e < e1; e += 256) {
        int s = __builtin_nontemporal_load(src + e);
        int d = __builtin_nontemporal_load(dst + e);
        if (s >= lo && s < hi) adj_h[atomicAdd(cur_h + s, 1)] = d;
        if (d >= lo && d < hi) adj_b[atomicAdd(cur_b + d, 1)] = s;
    }
}

// ---------- f32 -> bf16 elementwise convert ----------
__global__ void cvt_to_bf16(const float* __restrict__ in, unsigned short* __restrict__ out,
                            size_t n4) {
    size_t t = (size_t)blockIdx.x * blockDim.x + threadIdx.x;
    if (t >= n4) return;
    const float4 v = *(const float4*)(in + t * 4);
    ushort4 u;
    u.x = f2b(v.x); u.y = f2b(v.y); u.z = f2b(v.z); u.w = f2b(v.w);
    *(ushort4*)(out + t * 4) = u;
}

// ---------- CSR gather + mean + bf16 out ----------
// One wave per node; wave split into G row-groups of LPR lanes, 16B/lane.
// Main loop pipelined UNR=16/G deep (16 rows in flight per wave).
template <int D>
__global__ __launch_bounds__(256)
void gather_mean(const unsigned short* __restrict__ x, const int* __restrict__ row,
                 const int* __restrict__ adj, unsigned short* __restrict__ out, int N) {
    constexpr int LPR = D / 8;        // lanes per row (8 bf16 = 16B each)
    constexpr int G   = 64 / LPR;     // rows processed in parallel per instr
    constexpr int UNR = 16 / G;       // pipeline depth (rows in flight = 16)
    int wid  = (blockIdx.x * blockDim.x + threadIdx.x) >> 6;
    int lane = threadIdx.x & 63;
    if (wid >= N) return;
    int beg = row[wid];
    int deg = row[wid + 1] - beg;

    const int g  = lane >> (LPR == 16 ? 4 : 5);   // group id
    const int gl = lane & (LPR - 1);              // lane within group

    float acc[8];
    #pragma unroll
    for (int p = 0; p < 8; ++p) acc[p] = 0.0f;

    for (int base = 0; base < deg; base += 64) {
        int nb_l = (base + lane < deg) ? adj[beg + base + lane] : 0;
        int m = deg - base; if (m > 64) m = 64;
        int j = 0;
        for (; j + UNR * G <= m; j += UNR * G) {
            int nn[UNR];
            #pragma unroll
            for (int u = 0; u < UNR; ++u) nn[u] = __shfl(nb_l, j + u * G + g);
            short8 vv[UNR];
            #pragma unroll
            for (int u = 0; u < UNR; ++u)
                vv[u] = *(const short8*)(x + (size_t)nn[u] * D + gl * 8);
            #pragma unroll
            for (int u = 0; u < UNR; ++u)
                #pragma unroll
                for (int p = 0; p < 8; ++p) acc[p] += b2f((unsigned short)vv[u][p]);
        }
        for (; j < m; j += G) {
            int idx = j + g;
            int nb = __shfl(nb_l, idx);
            if (idx < m) {
                const short8 v = *(const short8*)(x + (size_t)nb * D + gl * 8);
                #pragma unroll
                for (int p = 0; p < 8; ++p) acc[p] += b2f((unsigned short)v[p]);
            }
        }
    }
    #pragma unroll
    for (int off = LPR; off < 64; off <<= 1) {
        #pragma unroll
        for (int p = 0; p < 8; ++p) acc[p] += __shfl_xor(acc[p], off);
    }
    float inv = 1.0f / (float)((deg > 0) ? deg : 1);
    if (lane < LPR) {
        unsigned short* op = out + (size_t)wid * D + lane * 8;
        short8 u;
        #pragma unroll
        for (int p = 0; p < 8; ++p) u[p] = (short)f2b(acc[p] * inv);
        *(short8*)op = u;
    }
}

// ---------- weight transpose + convert: W f32 [K][256] -> Wt bf16 [256][K] ----------
__global__ void transpose_w(const float* __restrict__ W,
                            unsigned short* __restrict__ Wt, int K) {
    int k = blockIdx.x;        // [0,K)
    int c = threadIdx.x;       // [0,256)
    Wt[(size_t)c * K + k] = f2b(W[(size_t)k * 256 + c]);
}

// ---------- fused GEMM: res = relu(A0@B0^T + A1@B1^T + bias) ----------
template <bool F32OUT>
__global__ __launch_bounds__(256, 3)
void gemm_fused(const unsigned short* __restrict__ A0, const unsigned short* __restrict__ A1,
                const unsigned short* __restrict__ B0, const unsigned short* __restrict__ B1,
                const float* __restrict__ bias,
                float* __restrict__ outf, unsigned short* __restrict__ outb,
                int M, int K) {
    __shared__ unsigned short As[64 * 64];    // 8 KB
    __shared__ unsigned short Bs[256 * 64];   // 32 KB
    const int tid  = threadIdx.x;
    const int wave = tid >> 6, lane = tid & 63;
    const int wn   = wave;
    const int row0 = blockIdx.x * 64;

    float4v acc[4][4];
    #pragma unroll
    for (int i = 0; i < 4; ++i)
        #pragma unroll
        for (int j = 0; j < 4; ++j) acc[i][j] = (float4v){0.f, 0.f, 0.f, 0.f};

    const int r  = lane >> 3;
    const int cg = lane & 7;
    const int kchunks = K >> 6;
    const int nchunks = kchunks * 2;

    for (int c = 0; c < nchunks; ++c) {
        const unsigned short* Aseg = (c < kchunks) ? A0 : A1;
        const unsigned short* Bseg = (c < kchunks) ? B0 : B1;
        const int k0 = ((c < kchunks) ? c : c - kchunks) << 6;

        if (c) __syncthreads();
        {   // stage A: 64 rows; 16 rows per wave
            int rr = wave * 16;
            const unsigned short* gp = Aseg + (size_t)(row0 + rr + r) * K + k0 + cg * 8;
            unsigned short* lp = As + rr * 64;
            if (row0 + rr + r < M)     gload_lds16(gp, lp);
            if (row0 + rr + 8 + r < M) gload_lds16(gp + 8 * (size_t)K, lp + 8 * 64);
        }
        {   // stage B: 256 rows; 64 rows per wave
            int rr = wave * 64;
            const unsigned short* gp = Bseg + (size_t)(rr + r) * K + k0 + cg * 8;
            unsigned short* lp = Bs + rr * 64;
            #pragma unroll
            for (int i = 0; i < 8; ++i)
                gload_lds16(gp + (size_t)(i * 8) * K, lp + i * 8 * 64);
        }
        __syncthreads();

        const int q8 = (lane >> 4) * 8;
        const int l15 = lane & 15;
        #pragma unroll
        for (int kk = 0; kk <= 32; kk += 32) {
            short8 af[4], bf[4];
            #pragma unroll
            for (int f = 0; f < 4; ++f)
                af[f] = *(const short8*)(As + (f * 16 + l15) * 64 + kk + q8);
            #pragma unroll
            for (int f = 0; f < 4; ++f)
                bf[f] = *(const short8*)(Bs + (wn * 64 + f * 16 + l15) * 64 + kk + q8);
            #pragma unroll
            for (int fm = 0; fm < 4; ++fm)
                #pragma unroll
                for (int fn = 0; fn < 4; ++fn)
                    acc[fm][fn] = __builtin_amdgcn_mfma_f32_16x16x32_bf16(
                        af[fm], bf[fn], acc[fm][fn], 0, 0, 0);
        }
    }

    // epilogue: C/D layout col=lane&15, row=(lane>>4)*4+reg  [verified m89/m91]
    const int l15 = lane & 15;
    const int rq  = (lane >> 4) * 4;
    #pragma unroll
    for (int fn = 0; fn < 4; ++fn) {
        int col = wn * 64 + fn * 16 + l15;
        float bv = bias[col];
        #pragma unroll
        for (int fm = 0; fm < 4; ++fm) {
            #pragma unroll
            for (int rg = 0; rg < 4; ++rg) {
                int row = row0 + fm * 16 + rq + rg;
                if (row < M) {
                    float v = fmaxf(acc[fm][fn][rg] + bv, 0.0f);
                    if (F32OUT) outf[(size_t)row * 256 + col] = v;
                    else        outb[(size_t)row * 256 + col] = f2b(v);
                }
            }
        }
    }
}

// ---------- launcher ----------
extern "C" void kernel_launch(void* const* d_in, const int* in_sizes, int n_in,
                              void* d_out, int out_size, void* d_ws, size_t ws_size,
                              hipStream_t stream) {
    const int DIN = 128, H = 256;
    const int N = in_sizes[0] / DIN;
    const int E = in_sizes[2] / 2;

    const float* xh = (const float*)d_in[0];
    const float* xb = (const float*)d_in[1];
    const int* ei  = (const int*)d_in[2];
    const int* src = ei;
    const int* dst = ei + E;
    const float* h1Wl = (const float*)d_in[3];
    const float* h1Wr = (const float*)d_in[4];
    const float* h1b  = (const float*)d_in[5];
    const float* h2Wl = (const float*)d_in[6];
    const float* h2Wr = (const float*)d_in[7];
    const float* h2b  = (const float*)d_in[8];
    const float* b1Wl = (const float*)d_in[9];
    const float* b1Wr = (const float*)d_in[10];
    const float* b1b  = (const float*)d_in[11];
    const float* b2Wl = (const float*)d_in[12];
    const float* b2Wr = (const float*)d_in[13];
    const float* b2b  = (const float*)d_in[14];

    float* outH = (float*)d_out;
    float* outB = outH + (size_t)N * H;

    // ---- ws layout ----
    int* deg_h = (int*)d_ws;
    int* deg_b = deg_h + N;
    int* row_h = deg_b + N;
    int* row_b = row_h + (N + 1);
    int* cur_h = row_b + (N + 1);
    int* cur_b = cur_h + N;
    int* partial = cur_b + N;          // up to 256 chunk sums
    int* adj_h = partial + 256;
    int* adj_b = adj_h + E;
    // round bf16 region up to 64B so all 16B vector accesses are naturally aligned
    uintptr_t up = (uintptr_t)(adj_b + E);
    up = (up + 63) & ~(uintptr_t)63;
    unsigned short* wtp = (unsigned short*)up;
    unsigned short* t_h1l = wtp; wtp += DIN * H;
    unsigned short* t_h1r = wtp; wtp += DIN * H;
    unsigned short* t_h2l = wtp; wtp += H * H;
    unsigned short* t_h2r = wtp; wtp += H * H;
    unsigned short* t_b1l = wtp; wtp += DIN * H;
    unsigned short* t_b1r = wtp; wtp += DIN * H;
    unsigned short* t_b2l = wtp; wtp += H * H;
    unsigned short* t_b2r = wtp; wtp += H * H;
    unsigned short* xbf   = wtp;
    unsigned short* aggbf = xbf + (size_t)N * DIN;
    unsigned short* hbf   = aggbf + (size_t)N * H;

    const int BLK = 256;
    dim3 blk(BLK);
    const int P = (N + 1023) / 1024;   // scan chunks

    // ---- build CSRs ----
    hipMemsetAsync(deg_h, 0, (size_t)2 * N * sizeof(int), stream);
    count_deg<<<dim3((E + BLK - 1) / BLK), blk, 0, stream>>>(src, dst, deg_h, deg_b, E);

    scan1<<<dim3(P), blk, 0, stream>>>(deg_h, partial, N);
    scan2<<<dim3(1), blk, 0, stream>>>(partial, P);
    scan3<<<dim3(P), blk, 0, stream>>>(deg_h, partial, row_h, N, E);
    scan1<<<dim3(P), blk, 0, stream>>>(deg_b, partial, N);
    scan2<<<dim3(1), blk, 0, stream>>>(partial, P);
    scan3<<<dim3(P), blk, 0, stream>>>(deg_b, partial, row_b, N, E);

    hipMemcpyAsync(cur_h, row_h, (size_t)N * sizeof(int), hipMemcpyDeviceToDevice, stream);
    hipMemcpyAsync(cur_b, row_b, (size_t)N * sizeof(int), hipMemcpyDeviceToDevice, stream);
    {   // ranged fill: 256 edge-chunks x 8 node-ranges = 2048 blocks
        const int NCH = 256;
        fill_adj_ranged<<<dim3(NCH * 8), blk, 0, stream>>>(src, dst, cur_h, cur_b,
                                                           adj_h, adj_b, E, N, NCH);
    }

    // ---- weight transposes ----
    transpose_w<<<dim3(DIN), blk, 0, stream>>>(h1Wl, t_h1l, DIN);
    transpose_w<<<dim3(DIN), blk, 0, stream>>>(h1Wr, t_h1r, DIN);
    transpose_w<<<dim3(H),   blk, 0, stream>>>(h2Wl, t_h2l, H);
    transpose_w<<<dim3(H),   blk, 0, stream>>>(h2Wr, t_h2r, H);
    transpose_w<<<dim3(DIN), blk, 0, stream>>>(b1Wl, t_b1l, DIN);
    transpose_w<<<dim3(DIN), blk, 0, stream>>>(b1Wr, t_b1r, DIN);
    transpose_w<<<dim3(H),   blk, 0, stream>>>(b2Wl, t_b2l, H);
    transpose_w<<<dim3(H),   blk, 0, stream>>>(b2Wr, t_b2r, H);

    dim3 nggrid((N + 3) / 4);                      // gather: wave per node, 4 waves/block
    dim3 ggrid((N + 63) / 64);                     // GEMM: 64 rows per block
    int ncvt = ((size_t)N * DIN / 4 + BLK - 1) / BLK;

    // ---- human branch ----
    cvt_to_bf16<<<dim3(ncvt), blk, 0, stream>>>(xh, xbf, (size_t)N * DIN / 4);
    gather_mean<128><<<nggrid, blk, 0, stream>>>(xbf, row_h, adj_h, aggbf, N);
    gemm_fused<false><<<ggrid, blk, 0, stream>>>(aggbf, xbf, t_h1l, t_h1r, h1b,
                                                 nullptr, hbf, N, DIN);
    gather_mean<256><<<nggrid, blk, 0, stream>>>(hbf, row_h, adj_h, aggbf, N);
    gemm_fused<true><<<ggrid, blk, 0, stream>>>(aggbf, hbf, t_h2l, t_h2r, h2b,
                                                outH, nullptr, N, H);

    // ---- bacterial branch ----
    cvt_to_bf16<<<dim3(ncvt), blk, 0, stream>>>(xb, xbf, (size_t)N * DIN / 4);
    gather_mean<128><<<nggrid, blk, 0, stream>>>(xbf, row_b, adj_b, aggbf, N);
    gemm_fused<false><<<ggrid, blk, 0, stream>>>(aggbf, xbf, t_b1l, t_b1r, b1b,
                                                 nullptr, hbf, N, DIN);
    gather_mean<256><<<nggrid, blk, 0, stream>>>(hbf, row_b, adj_b, aggbf, N);
    gemm_fused<true><<<ggrid, blk, 0, stream>>>(aggbf, hbf, t_b2l, t_b2r, b2b,
                                                outB, nullptr, N, H);
}

// Round 5
// 1019.249 us; speedup vs baseline: 1.3952x; 1.2609x over previous
//
#include <hip/hip_runtime.h>
#include <stdint.h>

// ---------- types / helpers ----------
using short8  = __attribute__((ext_vector_type(8))) short;
using float4v = __attribute__((ext_vector_type(4))) float;

__device__ __forceinline__ float b2f(unsigned short u) {
    union { unsigned int i; float f; } v; v.i = ((unsigned int)u) << 16; return v.f;
}
__device__ __forceinline__ unsigned short f2b(float f) {
    union { float f; unsigned int i; } v; v.f = f;
    unsigned int x = v.i;
    unsigned int r = (x + 0x7fffu + ((x >> 16) & 1u)) >> 16;   // RNE
    return (unsigned short)r;
}

__device__ __forceinline__ void gload_lds16(const void* g, void* l) {
    __builtin_amdgcn_global_load_lds((const __attribute__((address_space(1))) void*)g,
                                     (__attribute__((address_space(3))) void*)l, 16, 0, 0);
}

// ================= ELL path (primary) =================
// Padded adjacency, W=64 slots/node (deg ~ Poisson(16); P(deg>64) ~ 1e-20).
// One memset + one fill replaces count+scan+memcpy+fill (9 dispatches, ~100us).
// cnt doubles as the degree array for the gather.
__global__ __launch_bounds__(256)
void fill_ell_ranged(const int* __restrict__ src, const int* __restrict__ dst,
                     int* __restrict__ cnt_h, int* __restrict__ cnt_b,
                     int* __restrict__ adj_h, int* __restrict__ adj_b,
                     int E, int N, int nch) {
    const int NR = 8;
    int r     = blockIdx.x & (NR - 1);
    int chunk = blockIdx.x >> 3;
    int rng = (N + NR - 1) / NR;
    int lo = r * rng;
    int hi = lo + rng; if (hi > N) hi = N;
    int per = (E + nch - 1) / nch;
    int e0 = chunk * per;
    int e1 = e0 + per; if (e1 > E) e1 = E;
    for (int e = e0 + (int)threadIdx.x; e < e1; e += 256) {
        int s = __builtin_nontemporal_load(src + e);
        int d = __builtin_nontemporal_load(dst + e);
        if (s >= lo && s < hi) {
            int sl = atomicAdd(cnt_h + s, 1);
            if (sl < 64) adj_h[((size_t)s << 6) + sl] = d;
        }
        if (d >= lo && d < hi) {
            int sl = atomicAdd(cnt_b + d, 1);
            if (sl < 64) adj_b[((size_t)d << 6) + sl] = s;
        }
    }
}

// ================= CSR fallback path (if ws too small for ELL) =================
__global__ void count_deg(const int* __restrict__ src, const int* __restrict__ dst,
                          int* __restrict__ deg_h, int* __restrict__ deg_b, int E) {
    int e = blockIdx.x * blockDim.x + threadIdx.x;
    if (e < E) {
        int s = __builtin_nontemporal_load(src + e);
        int d = __builtin_nontemporal_load(dst + e);
        atomicAdd(deg_h + s, 1);
        atomicAdd(deg_b + d, 1);
    }
}
__global__ void scan1(const int* __restrict__ deg, int* __restrict__ partial, int N) {
    int t = threadIdx.x;
    int base = blockIdx.x * 1024 + t * 4;
    int s = 0;
    #pragma unroll
    for (int i = 0; i < 4; ++i) { int idx = base + i; if (idx < N) s += deg[idx]; }
    #pragma unroll
    for (int off = 32; off; off >>= 1) s += __shfl_down(s, off);
    __shared__ int sm[4];
    if ((t & 63) == 0) sm[t >> 6] = s;
    __syncthreads();
    if (t == 0) partial[blockIdx.x] = sm[0] + sm[1] + sm[2] + sm[3];
}
__global__ void scan2(int* __restrict__ partial, int P) {
    if (blockIdx.x == 0 && threadIdx.x == 0) {
        int run = 0;
        for (int i = 0; i < P; ++i) { int v = partial[i]; partial[i] = run; run += v; }
    }
}
__global__ void scan3(const int* __restrict__ deg, const int* __restrict__ partial,
                      int* __restrict__ row, int N, int E) {
    int t = threadIdx.x;
    int lane = t & 63, wv = t >> 6;
    int base = blockIdx.x * 1024 + t * 4;
    int d[4]; int s = 0;
    #pragma unroll
    for (int i = 0; i < 4; ++i) { int idx = base + i; d[i] = (idx < N) ? deg[idx] : 0; s += d[i]; }
    int inc = s;
    #pragma unroll
    for (int off = 1; off < 64; off <<= 1) { int v = __shfl_up(inc, off); if (lane >= off) inc += v; }
    __shared__ int wsum[4];
    if (lane == 63) wsum[wv] = inc;
    __syncthreads();
    int woff = 0;
    for (int w = 0; w < wv; ++w) woff += wsum[w];
    int run = inc - s + woff + partial[blockIdx.x];
    #pragma unroll
    for (int i = 0; i < 4; ++i) { int idx = base + i; if (idx < N) row[idx] = run; run += d[i]; }
    if (blockIdx.x == 0 && t == 0) row[N] = E;
}
__global__ __launch_bounds__(256)
void fill_adj_ranged(const int* __restrict__ src, const int* __restrict__ dst,
                     int* __restrict__ cur_h, int* __restrict__ cur_b,
                     int* __restrict__ adj_h, int* __restrict__ adj_b,
                     int E, int N, int nch) {
    const int NR = 8;
    int r     = blockIdx.x & (NR - 1);
    int chunk = blockIdx.x >> 3;
    int rng = (N + NR - 1) / NR;
    int lo = r * rng;
    int hi = lo + rng; if (hi > N) hi = N;
    int per = (E + nch - 1) / nch;
    int e0 = chunk * per;
    int e1 = e0 + per; if (e1 > E) e1 = E;
    for (int e = e0 + (int)threadIdx.x; e < e1; e += 256) {
        int s = __builtin_nontemporal_load(src + e);
        int d = __builtin_nontemporal_load(dst + e);
        if (s >= lo && s < hi) adj_h[atomicAdd(cur_h + s, 1)] = d;
        if (d >= lo && d < hi) adj_b[atomicAdd(cur_b + d, 1)] = s;
    }
}

// ---------- f32 -> bf16 elementwise convert ----------
__global__ void cvt_to_bf16(const float* __restrict__ in, unsigned short* __restrict__ out,
                            size_t n4) {
    size_t t = (size_t)blockIdx.x * blockDim.x + threadIdx.x;
    if (t >= n4) return;
    const float4 v = *(const float4*)(in + t * 4);
    ushort4 u;
    u.x = f2b(v.x); u.y = f2b(v.y); u.z = f2b(v.z); u.w = f2b(v.w);
    *(ushort4*)(out + t * 4) = u;
}

// ---------- gather + mean + bf16 out (ELL or CSR via ell flag) ----------
// One wave per node; G row-groups of LPR lanes at 16B/lane; UNR-deep pipeline.
template <int D>
__global__ __launch_bounds__(256)
void gather_mean(const unsigned short* __restrict__ x, const int* __restrict__ rowc,
                 const int* __restrict__ adj, unsigned short* __restrict__ out,
                 int N, int ell) {
    constexpr int LPR = D / 8;        // lanes per row
    constexpr int G   = 64 / LPR;     // rows in parallel per instr
    constexpr int UNR = 16 / G;       // rows in flight = 16
    int wid  = (blockIdx.x * blockDim.x + threadIdx.x) >> 6;
    int lane = threadIdx.x & 63;
    if (wid >= N) return;
    int beg, deg;
    if (ell) { beg = wid << 6; int c = rowc[wid]; deg = (c < 64) ? c : 64; }
    else     { beg = rowc[wid]; deg = rowc[wid + 1] - beg; }

    const int g  = lane >> (LPR == 16 ? 4 : 5);
    const int gl = lane & (LPR - 1);

    float acc[8];
    #pragma unroll
    for (int p = 0; p < 8; ++p) acc[p] = 0.0f;

    for (int base = 0; base < deg; base += 64) {
        int nb_l = (base + lane < deg) ? adj[beg + base + lane] : 0;
        int m = deg - base; if (m > 64) m = 64;
        int j = 0;
        for (; j + UNR * G <= m; j += UNR * G) {
            int nn[UNR];
            #pragma unroll
            for (int u = 0; u < UNR; ++u) nn[u] = __shfl(nb_l, j + u * G + g);
            short8 vv[UNR];
            #pragma unroll
            for (int u = 0; u < UNR; ++u)
                vv[u] = *(const short8*)(x + (size_t)nn[u] * D + gl * 8);
            #pragma unroll
            for (int u = 0; u < UNR; ++u)
                #pragma unroll
                for (int p = 0; p < 8; ++p) acc[p] += b2f((unsigned short)vv[u][p]);
        }
        for (; j < m; j += G) {
            int idx = j + g;
            int nb = __shfl(nb_l, idx);
            if (idx < m) {
                const short8 v = *(const short8*)(x + (size_t)nb * D + gl * 8);
                #pragma unroll
                for (int p = 0; p < 8; ++p) acc[p] += b2f((unsigned short)v[p]);
            }
        }
    }
    #pragma unroll
    for (int off = LPR; off < 64; off <<= 1) {
        #pragma unroll
        for (int p = 0; p < 8; ++p) acc[p] += __shfl_xor(acc[p], off);
    }
    float inv = 1.0f / (float)((deg > 0) ? deg : 1);
    if (lane < LPR) {
        unsigned short* op = out + (size_t)wid * D + lane * 8;
        short8 u;
        #pragma unroll
        for (int p = 0; p < 8; ++p) u[p] = (short)f2b(acc[p] * inv);
        *(short8*)op = u;
    }
}

// ---------- 4-matrix weight transpose: W f32 [K][256] -> Wt bf16 [256][K] ----------
__global__ void transpose_w4(const float* __restrict__ W0, const float* __restrict__ W1,
                             const float* __restrict__ W2, const float* __restrict__ W3,
                             unsigned short* __restrict__ T0, unsigned short* __restrict__ T1,
                             unsigned short* __restrict__ T2, unsigned short* __restrict__ T3,
                             int K) {
    int k = blockIdx.x;        // [0,K)
    int c = threadIdx.x;       // [0,256)
    int m = blockIdx.y;
    const float* W = (m == 0) ? W0 : (m == 1) ? W1 : (m == 2) ? W2 : W3;
    unsigned short* T = (m == 0) ? T0 : (m == 1) ? T1 : (m == 2) ? T2 : T3;
    T[(size_t)c * K + k] = f2b(W[(size_t)k * 256 + c]);
}

// ---------- fused GEMM: res = relu(A0@B0^T + A1@B1^T + bias) ----------
template <bool F32OUT>
__global__ __launch_bounds__(256, 3)
void gemm_fused(const unsigned short* __restrict__ A0, const unsigned short* __restrict__ A1,
                const unsigned short* __restrict__ B0, const unsigned short* __restrict__ B1,
                const float* __restrict__ bias,
                float* __restrict__ outf, unsigned short* __restrict__ outb,
                int M, int K) {
    __shared__ unsigned short As[64 * 64];    // 8 KB
    __shared__ unsigned short Bs[256 * 64];   // 32 KB
    const int tid  = threadIdx.x;
    const int wave = tid >> 6, lane = tid & 63;
    const int wn   = wave;
    const int row0 = blockIdx.x * 64;

    float4v acc[4][4];
    #pragma unroll
    for (int i = 0; i < 4; ++i)
        #pragma unroll
        for (int j = 0; j < 4; ++j) acc[i][j] = (float4v){0.f, 0.f, 0.f, 0.f};

    const int r  = lane >> 3;
    const int cg = lane & 7;
    const int kchunks = K >> 6;
    const int nchunks = kchunks * 2;

    for (int c = 0; c < nchunks; ++c) {
        const unsigned short* Aseg = (c < kchunks) ? A0 : A1;
        const unsigned short* Bseg = (c < kchunks) ? B0 : B1;
        const int k0 = ((c < kchunks) ? c : c - kchunks) << 6;

        if (c) __syncthreads();
        {   // stage A: 64 rows; 16 rows per wave
            int rr = wave * 16;
            const unsigned short* gp = Aseg + (size_t)(row0 + rr + r) * K + k0 + cg * 8;
            unsigned short* lp = As + rr * 64;
            if (row0 + rr + r < M)     gload_lds16(gp, lp);
            if (row0 + rr + 8 + r < M) gload_lds16(gp + 8 * (size_t)K, lp + 8 * 64);
        }
        {   // stage B: 256 rows; 64 rows per wave
            int rr = wave * 64;
            const unsigned short* gp = Bseg + (size_t)(rr + r) * K + k0 + cg * 8;
            unsigned short* lp = Bs + rr * 64;
            #pragma unroll
            for (int i = 0; i < 8; ++i)
                gload_lds16(gp + (size_t)(i * 8) * K, lp + i * 8 * 64);
        }
        __syncthreads();

        const int q8 = (lane >> 4) * 8;
        const int l15 = lane & 15;
        #pragma unroll
        for (int kk = 0; kk <= 32; kk += 32) {
            short8 af[4], bf[4];
            #pragma unroll
            for (int f = 0; f < 4; ++f)
                af[f] = *(const short8*)(As + (f * 16 + l15) * 64 + kk + q8);
            #pragma unroll
            for (int f = 0; f < 4; ++f)
                bf[f] = *(const short8*)(Bs + (wn * 64 + f * 16 + l15) * 64 + kk + q8);
            #pragma unroll
            for (int fm = 0; fm < 4; ++fm)
                #pragma unroll
                for (int fn = 0; fn < 4; ++fn)
                    acc[fm][fn] = __builtin_amdgcn_mfma_f32_16x16x32_bf16(
                        af[fm], bf[fn], acc[fm][fn], 0, 0, 0);
        }
    }

    // epilogue: C/D layout col=lane&15, row=(lane>>4)*4+reg  [verified m89/m91]
    const int l15 = lane & 15;
    const int rq  = (lane >> 4) * 4;
    #pragma unroll
    for (int fn = 0; fn < 4; ++fn) {
        int col = wn * 64 + fn * 16 + l15;
        float bv = bias[col];
        #pragma unroll
        for (int fm = 0; fm < 4; ++fm) {
            #pragma unroll
            for (int rg = 0; rg < 4; ++rg) {
                int row = row0 + fm * 16 + rq + rg;
                if (row < M) {
                    float v = fmaxf(acc[fm][fn][rg] + bv, 0.0f);
                    if (F32OUT) outf[(size_t)row * 256 + col] = v;
                    else        outb[(size_t)row * 256 + col] = f2b(v);
                }
            }
        }
    }
}

// ---------- launcher ----------
extern "C" void kernel_launch(void* const* d_in, const int* in_sizes, int n_in,
                              void* d_out, int out_size, void* d_ws, size_t ws_size,
                              hipStream_t stream) {
    const int DIN = 128, H = 256;
    const int N = in_sizes[0] / DIN;
    const int E = in_sizes[2] / 2;

    const float* xh = (const float*)d_in[0];
    const float* xb = (const float*)d_in[1];
    const int* ei  = (const int*)d_in[2];
    const int* src = ei;
    const int* dst = ei + E;
    const float* h1Wl = (const float*)d_in[3];
    const float* h1Wr = (const float*)d_in[4];
    const float* h1b  = (const float*)d_in[5];
    const float* h2Wl = (const float*)d_in[6];
    const float* h2Wr = (const float*)d_in[7];
    const float* h2b  = (const float*)d_in[8];
    const float* b1Wl = (const float*)d_in[9];
    const float* b1Wr = (const float*)d_in[10];
    const float* b1b  = (const float*)d_in[11];
    const float* b2Wl = (const float*)d_in[12];
    const float* b2Wr = (const float*)d_in[13];
    const float* b2b  = (const float*)d_in[14];

    float* outH = (float*)d_out;
    float* outB = outH + (size_t)N * H;

    const int BLK = 256;
    dim3 blk(BLK);

    // bf16 tail: weights + xbf + aggbf + hbf
    const size_t bfElems = (size_t)4 * DIN * H + (size_t)4 * H * H
                         + (size_t)N * DIN + (size_t)2 * N * H;
    const size_t bfBytes = bfElems * 2 + 64;

    // ELL needs: cnt 2N + adj 2*64*N ints
    const size_t needELL = ((size_t)2 * N + (size_t)128 * N) * 4 + bfBytes;
    const bool useELL = ws_size >= needELL;

    const int* rc_h; const int* rc_b; const int* ajh; const int* ajb;
    uintptr_t intEnd;

    if (useELL) {
        int* cnt_h = (int*)d_ws;
        int* cnt_b = cnt_h + N;
        int* adj_h = cnt_b + N;
        int* adj_b = adj_h + (size_t)N * 64;
        intEnd = (uintptr_t)(adj_b + (size_t)N * 64);

        hipMemsetAsync(cnt_h, 0, (size_t)2 * N * sizeof(int), stream);
        const int NCH = 256;
        fill_ell_ranged<<<dim3(NCH * 8), blk, 0, stream>>>(src, dst, cnt_h, cnt_b,
                                                           adj_h, adj_b, E, N, NCH);
        rc_h = cnt_h; rc_b = cnt_b; ajh = adj_h; ajb = adj_b;
    } else {
        int* deg_h = (int*)d_ws;
        int* deg_b = deg_h + N;
        int* row_h = deg_b + N;
        int* row_b = row_h + (N + 1);
        int* cur_h = row_b + (N + 1);
        int* cur_b = cur_h + N;
        int* partial = cur_b + N;
        int* adj_h = partial + 256;
        int* adj_b = adj_h + E;
        intEnd = (uintptr_t)(adj_b + E);

        const int P = (N + 1023) / 1024;
        hipMemsetAsync(deg_h, 0, (size_t)2 * N * sizeof(int), stream);
        count_deg<<<dim3((E + BLK - 1) / BLK), blk, 0, stream>>>(src, dst, deg_h, deg_b, E);
        scan1<<<dim3(P), blk, 0, stream>>>(deg_h, partial, N);
        scan2<<<dim3(1), blk, 0, stream>>>(partial, P);
        scan3<<<dim3(P), blk, 0, stream>>>(deg_h, partial, row_h, N, E);
        scan1<<<dim3(P), blk, 0, stream>>>(deg_b, partial, N);
        scan2<<<dim3(1), blk, 0, stream>>>(partial, P);
        scan3<<<dim3(P), blk, 0, stream>>>(deg_b, partial, row_b, N, E);
        hipMemcpyAsync(cur_h, row_h, (size_t)N * sizeof(int), hipMemcpyDeviceToDevice, stream);
        hipMemcpyAsync(cur_b, row_b, (size_t)N * sizeof(int), hipMemcpyDeviceToDevice, stream);
        const int NCH = 256;
        fill_adj_ranged<<<dim3(NCH * 8), blk, 0, stream>>>(src, dst, cur_h, cur_b,
                                                           adj_h, adj_b, E, N, NCH);
        rc_h = row_h; rc_b = row_b; ajh = adj_h; ajb = adj_b;
    }
    const int ellf = useELL ? 1 : 0;

    // bf16 region (64B aligned)
    uintptr_t up = (intEnd + 63) & ~(uintptr_t)63;
    unsigned short* wtp = (unsigned short*)up;
    unsigned short* t_h1l = wtp; wtp += DIN * H;
    unsigned short* t_h1r = wtp; wtp += DIN * H;
    unsigned short* t_h2l = wtp; wtp += H * H;
    unsigned short* t_h2r = wtp; wtp += H * H;
    unsigned short* t_b1l = wtp; wtp += DIN * H;
    unsigned short* t_b1r = wtp; wtp += DIN * H;
    unsigned short* t_b2l = wtp; wtp += H * H;
    unsigned short* t_b2r = wtp; wtp += H * H;
    unsigned short* xbf   = wtp;
    unsigned short* aggbf = xbf + (size_t)N * DIN;
    unsigned short* hbf   = aggbf + (size_t)N * H;

    // weight transposes: 2 launches (K=128 quad, K=256 quad)
    transpose_w4<<<dim3(DIN, 4), blk, 0, stream>>>(h1Wl, h1Wr, b1Wl, b1Wr,
                                                   t_h1l, t_h1r, t_b1l, t_b1r, DIN);
    transpose_w4<<<dim3(H, 4),   blk, 0, stream>>>(h2Wl, h2Wr, b2Wl, b2Wr,
                                                   t_h2l, t_h2r, t_b2l, t_b2r, H);

    dim3 nggrid((N + 3) / 4);
    dim3 ggrid((N + 63) / 64);
    int ncvt = ((size_t)N * DIN / 4 + BLK - 1) / BLK;

    // ---- human branch ----
    cvt_to_bf16<<<dim3(ncvt), blk, 0, stream>>>(xh, xbf, (size_t)N * DIN / 4);
    gather_mean<128><<<nggrid, blk, 0, stream>>>(xbf, rc_h, ajh, aggbf, N, ellf);
    gemm_fused<false><<<ggrid, blk, 0, stream>>>(aggbf, xbf, t_h1l, t_h1r, h1b,
                                                 nullptr, hbf, N, DIN);
    gather_mean<256><<<nggrid, blk, 0, stream>>>(hbf, rc_h, ajh, aggbf, N, ellf);
    gemm_fused<true><<<ggrid, blk, 0, stream>>>(aggbf, hbf, t_h2l, t_h2r, h2b,
                                                outH, nullptr, N, H);

    // ---- bacterial branch ----
    cvt_to_bf16<<<dim3(ncvt), blk, 0, stream>>>(xb, xbf, (size_t)N * DIN / 4);
    gather_mean<128><<<nggrid, blk, 0, stream>>>(xbf, rc_b, ajb, aggbf, N, ellf);
    gemm_fused<false><<<ggrid, blk, 0, stream>>>(aggbf, xbf, t_b1l, t_b1r, b1b,
                                                 nullptr, hbf, N, DIN);
    gather_mean<256><<<nggrid, blk, 0, stream>>>(hbf, rc_b, ajb, aggbf, N, ellf);
    gemm_fused<true><<<ggrid, blk, 0, stream>>>(aggbf, hbf, t_b2l, t_b2r, b2b,
                                                outB, nullptr, N, H);
}